// Round 1
// baseline (121.894 us; speedup 1.0000x reference)
//
#include <hip/hip_runtime.h>

// CAPE skip-gram NS loss: gather + dot products, memory-bound.
// 16 lanes per batch element; each lane owns a float4 (16B) slice of the
// D=64 row, so one wave-level load instruction fetches 4 full 256B rows.

__global__ __launch_bounds__(256) void CAPE_43525198578167_kernel(
    const float* __restrict__ emb_in,    // [POI, 64]
    const float* __restrict__ emb_out,   // [POI, 64]
    const int*   __restrict__ target,    // [B]
    const int*   __restrict__ context,   // [B]
    const int*   __restrict__ negs,      // [B, NS]
    float* __restrict__ target_loss,     // [B]
    float* __restrict__ neg_loss,        // [B, NS]
    int B, int NS)
{
    const int lane16  = threadIdx.x & 15;
    const int group   = (int)((blockIdx.x * blockDim.x + threadIdx.x) >> 4);
    const int ngroups = (int)((gridDim.x * blockDim.x) >> 4);

    const float4* ein4  = reinterpret_cast<const float4*>(emb_in);
    const float4* eout4 = reinterpret_cast<const float4*>(emb_out);

    for (int b = group; b < B; b += ngroups) {
        const int t = target[b];
        const int c = context[b];

        const float4 ei = ein4[(size_t)t * 16 + lane16];
        const float4 eo = eout4[(size_t)c * 16 + lane16];

        float p = ei.x * eo.x + ei.y * eo.y + ei.z * eo.z + ei.w * eo.w;
        // butterfly reduce across the aligned 16-lane group
        p += __shfl_xor(p, 1);
        p += __shfl_xor(p, 2);
        p += __shfl_xor(p, 4);
        p += __shfl_xor(p, 8);
        if (lane16 == 0) target_loss[b] = p;

        #pragma unroll
        for (int n = 0; n < 10; ++n) {
            const int idx = negs[b * 10 + n];            // same addr all lanes -> broadcast
            const float4 v = eout4[(size_t)idx * 16 + lane16];
            float q = ei.x * v.x + ei.y * v.y + ei.z * v.z + ei.w * v.w;
            q += __shfl_xor(q, 1);
            q += __shfl_xor(q, 2);
            q += __shfl_xor(q, 4);
            q += __shfl_xor(q, 8);
            if (lane16 == n) neg_loss[b * 10 + n] = -q;   // e_neg = -emb_out[idx]
        }
        (void)NS; // fixed at 10 per problem spec
    }
}

extern "C" void kernel_launch(void* const* d_in, const int* in_sizes, int n_in,
                              void* d_out, int out_size, void* d_ws, size_t ws_size,
                              hipStream_t stream) {
    const float* emb_in  = (const float*)d_in[0];
    const float* emb_out = (const float*)d_in[1];
    const int*   target  = (const int*)d_in[2];
    const int*   context = (const int*)d_in[3];
    const int*   negs    = (const int*)d_in[4];

    const int B  = in_sizes[2];          // 262144
    const int NS = in_sizes[4] / B;      // 10

    float* out = (float*)d_out;
    float* target_loss = out;            // [B]
    float* neg_loss    = out + B;        // [B, NS]

    const int block = 256;
    const int grid  = 2048;              // 256 CUs x 8 blocks/CU worth of waves
    CAPE_43525198578167_kernel<<<grid, block, 0, stream>>>(
        emb_in, emb_out, target, context, negs, target_loss, neg_loss, B, NS);
}